// Round 4
// baseline (293.633 us; speedup 1.0000x reference)
//
#include <hip/hip_runtime.h>

// ---------- helpers ----------
__device__ __forceinline__ unsigned short f2b(float f) {
    unsigned int u = __builtin_bit_cast(unsigned int, f);
    unsigned int r = (u + 0x7FFFu + ((u >> 16) & 1u)) >> 16;  // RNE
    return (unsigned short)r;
}
__device__ __forceinline__ float b2f(unsigned short s) {
    unsigned int u = ((unsigned int)s) << 16;
    return __builtin_bit_cast(float, u);
}

typedef __attribute__((ext_vector_type(8))) short short8;
typedef __attribute__((ext_vector_type(4))) float float4v;

#define GLD16(g, l) __builtin_amdgcn_global_load_lds(                          \
    (const __attribute__((address_space(1))) unsigned int*)(g),                \
    (__attribute__((address_space(3))) unsigned int*)(l), 16, 0, 0)

// L=16384, D_IN=512, D_H=1024, D_OUT=512
#define SEQLEN 16384
#define NCHUNK 512
#define TCHUNK 32
#define LDH 2560   // Hcat row stride (cols: [0,2048)=Bu/h, [2048,2560)=x_bf16)

// ---------- merged prep: xcast + prep_B + prep_CW ----------
__global__ void prep_all(const float* __restrict__ x,
                         const float* __restrict__ B_re, const float* __restrict__ B_im,
                         const float* __restrict__ gamma,
                         const float* __restrict__ C_re, const float* __restrict__ C_im,
                         const float* __restrict__ Dm,
                         unsigned short* __restrict__ Hcat,
                         unsigned short* __restrict__ Bcat,
                         unsigned short* __restrict__ CW) {
    int b = blockIdx.x;
    if (b < 8192) {
        int id = b * 256 + threadIdx.x;            // one per 4 elements of [16384 x 512]
        int t = id >> 7;
        int k4 = (id & 127) << 2;
        float4 v = *(const float4*)(x + (long)t * 512 + k4);
        ushort4 o;
        o.x = f2b(v.x); o.y = f2b(v.y); o.z = f2b(v.z); o.w = f2b(v.w);
        *(ushort4*)(Hcat + (long)t * LDH + 2048 + k4) = o;
    } else if (b < 9216) {
        int id = (b - 8192) * 256 + threadIdx.x;   // one per 4 elements of [2048 x 512]
        int n = id >> 7;
        int k4 = (id & 127) << 2;
        const float* src = (n < 1024) ? (B_re + (long)n * 512) : (B_im + (long)(n - 1024) * 512);
        float g = expf(gamma[n & 1023]);
        float4 v = *(const float4*)(src + k4);
        ushort4 o;
        o.x = f2b(v.x * g); o.y = f2b(v.y * g); o.z = f2b(v.z * g); o.w = f2b(v.w * g);
        *(ushort4*)(Bcat + (long)n * 512 + k4) = o;
    } else {
        int id = (b - 9216) * 256 + threadIdx.x;   // one per 4 elements of [512 x 2560]
        int o = id / 640;
        int j4 = (id - o * 640) << 2;
        float4 v; float sgn = 1.0f;
        if (j4 < 1024) {
            v = *(const float4*)(C_re + (long)o * 1024 + j4);
        } else if (j4 < 2048) {
            v = *(const float4*)(C_im + (long)o * 1024 + (j4 - 1024));
            sgn = -1.0f;
        } else {
            v = *(const float4*)(Dm + (long)o * 512 + (j4 - 2048));
        }
        ushort4 w;
        w.x = f2b(v.x * sgn); w.y = f2b(v.y * sgn); w.z = f2b(v.z * sgn); w.w = f2b(v.w * sgn);
        *(ushort4*)(CW + (long)o * 2560 + j4) = w;
    }
}

// ---------- single-wave GEMM: 64 threads, wave-tile 64(m) x 128(n), BK=32, LDS dbuf ----------
// C[m,n] = sum_k A[m,k]*B[n,k].  No barriers: one wave stages its own tiles via
// global_load_lds and orders with explicit s_waitcnt vmcnt(12) so the next slab's
// 12 loads stay in flight across the current slab's MFMAs.
// LDS per buffer: A 64x32 (4KB) + B 128x32 (8KB); dbuf = 24KB -> 6 blocks/CU.
template <bool OUT_BF16>
__launch_bounds__(64, 2)
__global__ void gemm_w64(const unsigned short* __restrict__ A, int lda,
                         const unsigned short* __restrict__ B, int ldb,
                         void* __restrict__ Cout, int ldc, int Ktot,
                         int nbx_shift) {
    __shared__ unsigned short sm[2][6144] __attribute__((aligned(16)));
    const int lane = threadIdx.x;

    // XCD swizzle: all bx of a by-group on one XCD (locality heuristic only)
    const int bid = blockIdx.x;
    const int xcd = bid & 7;
    const int g = bid >> 3;
    const int bx = g & ((1 << nbx_shift) - 1);
    const int by = xcd * 32 + (g >> nbx_shift);
    const long m0 = (long)by * 64;
    const long n0 = (long)bx * 128;

    // staging: one GLD16 instr = 16 rows x 32k slab chunk (1KB). lane -> row (lane>>2), col8 (lane&3)*8
    const unsigned short* Ag = A + (m0 + (lane >> 2)) * lda + (lane & 3) * 8;
    const unsigned short* Bg = B + (n0 + (lane >> 2)) * ldb + (lane & 3) * 8;

    const int fr = lane & 15;
    const int fk = (lane >> 4) * 8;

    float4v acc[4][8] = {};

    auto stage = [&](int b, int k0) {
#pragma unroll
        for (int i = 0; i < 4; i++)
            GLD16(Ag + (long)i * 16 * lda + k0, &sm[b][i * 512]);
#pragma unroll
        for (int j = 0; j < 8; j++)
            GLD16(Bg + (long)j * 16 * ldb + k0, &sm[b][2048 + j * 512]);
    };
    auto compute = [&](int b) {
        short8 af[4], bf8[8];
#pragma unroll
        for (int i = 0; i < 4; i++)
            af[i] = *(const short8*)(&sm[b][(i * 16 + fr) * 32 + fk]);
#pragma unroll
        for (int j = 0; j < 8; j++)
            bf8[j] = *(const short8*)(&sm[b][2048 + (j * 16 + fr) * 32 + fk]);
#pragma unroll
        for (int mi = 0; mi < 4; mi++)
#pragma unroll
            for (int ni = 0; ni < 8; ni++)
                acc[mi][ni] = __builtin_amdgcn_mfma_f32_16x16x32_bf16(af[mi], bf8[ni], acc[mi][ni], 0, 0, 0);
    };

    stage(0, 0);
    int buf = 0;
    int k0 = 0;
    for (; k0 + 32 < Ktot; k0 += 32) {
        stage(buf ^ 1, k0 + 32);
        // wait for the oldest 12 loads (current buf); leave the 12 just issued in flight
        __builtin_amdgcn_s_waitcnt(0x0F7C);  // vmcnt(12) expcnt(7) lgkmcnt(15)
        compute(buf);
        buf ^= 1;
    }
    __builtin_amdgcn_s_waitcnt(0x0F70);      // vmcnt(0): drain final slab
    compute(buf);

    // epilogue: C/D layout col=lane&15, row=(lane>>4)*4+reg
    const int er = (lane >> 4) * 4;
    const int ec = lane & 15;
#pragma unroll
    for (int mi = 0; mi < 4; mi++) {
#pragma unroll
        for (int r = 0; r < 4; r++) {
            long grow = m0 + mi * 16 + er + r;
#pragma unroll
            for (int ni = 0; ni < 8; ni++) {
                long gcol = n0 + ni * 16 + ec;
                float v = acc[mi][ni][r];
                if (OUT_BF16)
                    ((unsigned short*)Cout)[grow * ldc + gcol] = f2b(v);
                else
                    ((float*)Cout)[grow * ldc + gcol] = v;
            }
        }
    }
}

// ---------- scan pass B: per-chunk local end states (zero-init) ----------
__global__ void scan_ends(const unsigned short* __restrict__ Hcat,
                          const float* __restrict__ lamb,
                          float* __restrict__ E) {
    const int chunk = blockIdx.x;
    const int ch = threadIdx.x << 2;   // 4 channels per thread
    float lre[4], lim[4];
#pragma unroll
    for (int i = 0; i < 4; i++) {
        float nu = expf(-expf(lamb[ch + i]));
        float th = expf(lamb[1024 + ch + i]);
        lre[i] = nu * cosf(th);
        lim[i] = nu * sinf(th);
    }
    float hr[4] = {0, 0, 0, 0}, hi[4] = {0, 0, 0, 0};
    const unsigned short* base = Hcat + (long)chunk * TCHUNK * LDH + ch;
#pragma unroll 4
    for (int t = 0; t < TCHUNK; t++) {
        ushort4 br = *(const ushort4*)(base + (long)t * LDH);
        ushort4 bi = *(const ushort4*)(base + (long)t * LDH + 1024);
        float brf[4] = {b2f(br.x), b2f(br.y), b2f(br.z), b2f(br.w)};
        float bif[4] = {b2f(bi.x), b2f(bi.y), b2f(bi.z), b2f(bi.w)};
#pragma unroll
        for (int i = 0; i < 4; i++) {
            float nr = fmaf(lre[i], hr[i], fmaf(-lim[i], hi[i], brf[i]));
            float ni = fmaf(lre[i], hi[i], fmaf(lim[i], hr[i], bif[i]));
            hr[i] = nr; hi[i] = ni;
        }
    }
    float* Ec = E + (long)chunk * 2048 + ch;
#pragma unroll
    for (int i = 0; i < 4; i++) {
        Ec[i] = hr[i];
        Ec[1024 + i] = hi[i];
    }
}

// ---------- scan pass C: sequential carry combine over chunks ----------
__global__ void carry(const float* __restrict__ lamb, const float* __restrict__ E,
                      float* __restrict__ Kc) {
    const int ch = blockIdx.x * 256 + threadIdx.x;  // 0..1023
    double nu = exp(-exp((double)lamb[ch]));
    double th = exp((double)lamb[1024 + ch]);
    double lr = nu * cos(th), li = nu * sin(th);
#pragma unroll
    for (int i = 0; i < 5; i++) {          // lambda^32
        double rr = lr * lr - li * li;
        double ii = 2.0 * lr * li;
        lr = rr; li = ii;
    }
    float tre = (float)lr, tim = (float)li;
    float hr = 0.0f, hi = 0.0f;
#pragma unroll 8
    for (int c = 0; c < NCHUNK; c++) {
        Kc[(long)c * 2048 + ch] = hr;
        Kc[(long)c * 2048 + 1024 + ch] = hi;
        float er = E[(long)c * 2048 + ch];
        float ei = E[(long)c * 2048 + 1024 + ch];
        float nr = fmaf(tre, hr, fmaf(-tim, hi, er));
        float ni = fmaf(tre, hi, fmaf(tim, hr, ei));
        hr = nr; hi = ni;
    }
}

// ---------- scan pass D: re-scan each chunk seeded with carry, IN PLACE ----------
__global__ void scan_apply(unsigned short* __restrict__ Hcat,
                           const float* __restrict__ lamb,
                           const float* __restrict__ Kc) {
    const int chunk = blockIdx.x;
    const int ch = threadIdx.x << 2;
    float lre[4], lim[4];
#pragma unroll
    for (int i = 0; i < 4; i++) {
        float nu = expf(-expf(lamb[ch + i]));
        float th = expf(lamb[1024 + ch + i]);
        lre[i] = nu * cosf(th);
        lim[i] = nu * sinf(th);
    }
    float hr[4], hi[4];
#pragma unroll
    for (int i = 0; i < 4; i++) {
        hr[i] = Kc[(long)chunk * 2048 + ch + i];
        hi[i] = Kc[(long)chunk * 2048 + 1024 + ch + i];
    }
    unsigned short* base = Hcat + (long)chunk * TCHUNK * LDH + ch;
#pragma unroll 4
    for (int t = 0; t < TCHUNK; t++) {
        ushort4 br = *(const ushort4*)(base + (long)t * LDH);
        ushort4 bi = *(const ushort4*)(base + (long)t * LDH + 1024);
        float brf[4] = {b2f(br.x), b2f(br.y), b2f(br.z), b2f(br.w)};
        float bif[4] = {b2f(bi.x), b2f(bi.y), b2f(bi.z), b2f(bi.w)};
#pragma unroll
        for (int i = 0; i < 4; i++) {
            float nr = fmaf(lre[i], hr[i], fmaf(-lim[i], hi[i], brf[i]));
            float ni = fmaf(lre[i], hi[i], fmaf(lim[i], hr[i], bif[i]));
            hr[i] = nr; hi[i] = ni;
        }
        ushort4 orv, oiv;
        orv.x = f2b(hr[0]); orv.y = f2b(hr[1]); orv.z = f2b(hr[2]); orv.w = f2b(hr[3]);
        oiv.x = f2b(hi[0]); oiv.y = f2b(hi[1]); oiv.z = f2b(hi[2]); oiv.w = f2b(hi[3]);
        *(ushort4*)(base + (long)t * LDH) = orv;
        *(ushort4*)(base + (long)t * LDH + 1024) = oiv;
    }
}

// ---------- launch ----------
extern "C" void kernel_launch(void* const* d_in, const int* in_sizes, int n_in,
                              void* d_out, int out_size, void* d_ws, size_t ws_size,
                              hipStream_t stream) {
    const float* x     = (const float*)d_in[0];  // [16384, 512]
    const float* lamb  = (const float*)d_in[1];  // [2, 1024]
    const float* gamma = (const float*)d_in[2];  // [1024]
    const float* B_re  = (const float*)d_in[3];  // [1024, 512]
    const float* B_im  = (const float*)d_in[4];
    const float* C_re  = (const float*)d_in[5];  // [512, 1024]
    const float* C_im  = (const float*)d_in[6];
    const float* Dm    = (const float*)d_in[7];  // [512, 512]

    char* ws = (char*)d_ws;
    unsigned short* Hcat = (unsigned short*)ws;                      // 16384*2560*2 = 83886080
    float* E  = (float*)(ws + 83886080);                             // 512*2048*4 = 4194304
    float* Kc = E + (long)NCHUNK * 2048;                             // 4194304
    unsigned short* Bcat = (unsigned short*)((char*)Kc + 4194304);   // 2048*512*2 = 2097152
    unsigned short* CW   = Bcat + (long)2048 * 512;                  // 512*2560*2 = 2621440

    prep_all<<<10496, 256, 0, stream>>>(x, B_re, B_im, gamma, C_re, C_im, Dm, Hcat, Bcat, CW);
    // Bu = x_bf16 @ Bcat^T -> Hcat cols [0,2048).  grid 256(by) x 16(bx) = 4096 single-wave blocks.
    gemm_w64<true><<<4096, 64, 0, stream>>>(Hcat + 2048, LDH, Bcat, 512, Hcat, LDH, 512,
                                            /*nbx_shift=*/4);
    scan_ends<<<NCHUNK, 256, 0, stream>>>(Hcat, lamb, E);
    carry<<<4, 256, 0, stream>>>(lamb, E, Kc);
    scan_apply<<<NCHUNK, 256, 0, stream>>>(Hcat, lamb, Kc);
    // y = Hcat @ CW^T -> d_out f32.  grid 256(by) x 4(bx) = 1024 single-wave blocks.
    gemm_w64<false><<<1024, 64, 0, stream>>>(Hcat, LDH, CW, 2560, (float*)d_out, 512, 2560,
                                             /*nbx_shift=*/2);
}

// Round 5
// 285.613 us; speedup vs baseline: 1.0281x; 1.0281x over previous
//
#include <hip/hip_runtime.h>

// ---------- helpers ----------
__device__ __forceinline__ unsigned short f2b(float f) {
    unsigned int u = __builtin_bit_cast(unsigned int, f);
    unsigned int r = (u + 0x7FFFu + ((u >> 16) & 1u)) >> 16;  // RNE
    return (unsigned short)r;
}
__device__ __forceinline__ float b2f(unsigned short s) {
    unsigned int u = ((unsigned int)s) << 16;
    return __builtin_bit_cast(float, u);
}

typedef __attribute__((ext_vector_type(8))) short short8;
typedef __attribute__((ext_vector_type(4))) float float4v;

#define GLD16(g, l) __builtin_amdgcn_global_load_lds(                          \
    (const __attribute__((address_space(1))) unsigned int*)(g),                \
    (__attribute__((address_space(3))) unsigned int*)(l), 16, 0, 0)

#define WAIT_VM12() __builtin_amdgcn_s_waitcnt(0x0F7C)  // vmcnt(12), exp/lgkm free
#define WAIT_VM0()  __builtin_amdgcn_s_waitcnt(0x0F70)  // vmcnt(0),  exp/lgkm free

// L=16384, D_IN=512, D_H=1024, D_OUT=512
#define SEQLEN 16384
#define NCHUNK 512
#define TCHUNK 32
#define LDH 2560   // Hcat row stride (cols: [0,2048)=Bu/h, [2048,2560)=x_bf16)

// ---------- merged prep: xcast + prep_B + prep_CW ----------
__global__ void prep_all(const float* __restrict__ x,
                         const float* __restrict__ B_re, const float* __restrict__ B_im,
                         const float* __restrict__ gamma,
                         const float* __restrict__ C_re, const float* __restrict__ C_im,
                         const float* __restrict__ Dm,
                         unsigned short* __restrict__ Hcat,
                         unsigned short* __restrict__ Bcat,
                         unsigned short* __restrict__ CW) {
    int b = blockIdx.x;
    if (b < 8192) {
        int id = b * 256 + threadIdx.x;            // one per 4 elements of [16384 x 512]
        int t = id >> 7;
        int k4 = (id & 127) << 2;
        float4 v = *(const float4*)(x + (long)t * 512 + k4);
        ushort4 o;
        o.x = f2b(v.x); o.y = f2b(v.y); o.z = f2b(v.z); o.w = f2b(v.w);
        *(ushort4*)(Hcat + (long)t * LDH + 2048 + k4) = o;
    } else if (b < 9216) {
        int id = (b - 8192) * 256 + threadIdx.x;   // one per 4 elements of [2048 x 512]
        int n = id >> 7;
        int k4 = (id & 127) << 2;
        const float* src = (n < 1024) ? (B_re + (long)n * 512) : (B_im + (long)(n - 1024) * 512);
        float g = expf(gamma[n & 1023]);
        float4 v = *(const float4*)(src + k4);
        ushort4 o;
        o.x = f2b(v.x * g); o.y = f2b(v.y * g); o.z = f2b(v.z * g); o.w = f2b(v.w * g);
        *(ushort4*)(Bcat + (long)n * 512 + k4) = o;
    } else {
        int id = (b - 9216) * 256 + threadIdx.x;   // one per 4 elements of [512 x 2560]
        int o = id / 640;
        int j4 = (id - o * 640) << 2;
        float4 v; float sgn = 1.0f;
        if (j4 < 1024) {
            v = *(const float4*)(C_re + (long)o * 1024 + j4);
        } else if (j4 < 2048) {
            v = *(const float4*)(C_im + (long)o * 1024 + (j4 - 1024));
            sgn = -1.0f;
        } else {
            v = *(const float4*)(Dm + (long)o * 512 + (j4 - 2048));
        }
        ushort4 w;
        w.x = f2b(v.x * sgn); w.y = f2b(v.y * sgn); w.z = f2b(v.z * sgn); w.w = f2b(v.w * sgn);
        *(ushort4*)(CW + (long)o * 2560 + j4) = w;
    }
}

// ---------- single-wave pipelined GEMM: 64 threads, tile 64(m) x 128(n), BK=32 ----------
// 3-stage pipeline, no barriers:
//   stage(i+2): 12x global_load_lds into LDS buf (i+2)%3      [vmcnt tracks]
//   loadfrags(i+1): 12x ds_read_b128 into ping-pong regs      [lgkm waited at use]
//   mfma(i): 32 MFMAs on current regs
// LDS: 3 x (A 64x32 + B 128x32) = 36 KB -> 4 blocks/CU.
template <bool OUT_BF16>
__launch_bounds__(64)
__global__ void gemm_w64(const unsigned short* __restrict__ A, int lda,
                         const unsigned short* __restrict__ B, int ldb,
                         void* __restrict__ Cout, int ldc, int Ktot,
                         int nbx_shift) {
    __shared__ unsigned short sm[3][6144] __attribute__((aligned(16)));
    const int lane = threadIdx.x;

    // XCD swizzle: all bx of a by-group on one XCD (locality heuristic only)
    const int bid = blockIdx.x;
    const int xcd = bid & 7;
    const int g = bid >> 3;
    const int bx = g & ((1 << nbx_shift) - 1);
    const int by = xcd * 32 + (g >> nbx_shift);
    const long m0 = (long)by * 64;
    const long n0 = (long)bx * 128;

    // staging addressing: one GLD16 = 16 rows x 32 cols (1 KB), lane -> row lane>>2, col8 (lane&3)*8
    const unsigned short* Ag = A + (m0 + (lane >> 2)) * lda + (lane & 3) * 8;
    const unsigned short* Bg = B + (n0 + (lane >> 2)) * ldb + (lane & 3) * 8;

    const int fr = lane & 15;
    const int fk = (lane >> 4) * 8;

    float4v acc[4][8] = {};
    short8 faE[4], fbE[8], faO[4], fbO[8];

    unsigned short* p0 = sm[0];
    unsigned short* p1 = sm[1];
    unsigned short* p2 = sm[2];

    auto stage = [&](unsigned short* buf, int k0) {
#pragma unroll
        for (int i = 0; i < 4; i++)
            GLD16(Ag + (long)i * 16 * lda + k0, buf + i * 512);
#pragma unroll
        for (int j = 0; j < 8; j++)
            GLD16(Bg + (long)j * 16 * ldb + k0, buf + 2048 + j * 512);
    };
    auto loadfrags = [&](const unsigned short* buf, short8* fa, short8* fb) {
#pragma unroll
        for (int i = 0; i < 4; i++)
            fa[i] = *(const short8*)(buf + (i * 16 + fr) * 32 + fk);
#pragma unroll
        for (int j = 0; j < 8; j++)
            fb[j] = *(const short8*)(buf + 2048 + (j * 16 + fr) * 32 + fk);
    };
    auto domfma = [&](const short8* fa, const short8* fb) {
#pragma unroll
        for (int mi = 0; mi < 4; mi++)
#pragma unroll
            for (int ni = 0; ni < 8; ni++)
                acc[mi][ni] = __builtin_amdgcn_mfma_f32_16x16x32_bf16(fa[mi], fb[ni], acc[mi][ni], 0, 0, 0);
    };

    const int nk = Ktot >> 5;  // slabs of BK=32 (16 or 80 here -- both even)

    // prologue: slabs 0,1 staged; frags(0) -> E
    stage(p0, 0);
    stage(p1, 32);
    WAIT_VM12();               // slab 0 landed (slab 1's 12 still in flight)
    loadfrags(p0, faE, fbE);

    int k0 = 0;
    for (int i = 0; i < nk - 2; i += 2) {
        // slab i (even): compute E, prefetch frags(i+1) -> O, stage slab i+2
        stage(p2, k0 + 64);
        WAIT_VM12();           // slab i+1 landed (i+2's 12 in flight)
        loadfrags(p1, faO, fbO);
        domfma(faE, fbE);
        { unsigned short* t = p0; p0 = p1; p1 = p2; p2 = t; }
        k0 += 32;
        // slab i+1 (odd): compute O, prefetch frags(i+2) -> E, stage slab i+3
        stage(p2, k0 + 64);
        WAIT_VM12();
        loadfrags(p1, faE, fbE);
        domfma(faO, fbO);
        { unsigned short* t = p0; p0 = p1; p1 = p2; p2 = t; }
        k0 += 32;
    }
    // epilogue: E = frags(nk-2); slab nk-1 is in p1
    WAIT_VM0();
    loadfrags(p1, faO, fbO);
    domfma(faE, fbE);
    domfma(faO, fbO);

    // epilogue store: C/D layout col=lane&15, row=(lane>>4)*4+reg
    const int er = (lane >> 4) * 4;
    const int ec = lane & 15;
#pragma unroll
    for (int mi = 0; mi < 4; mi++) {
#pragma unroll
        for (int r = 0; r < 4; r++) {
            long grow = m0 + mi * 16 + er + r;
#pragma unroll
            for (int ni = 0; ni < 8; ni++) {
                long gcol = n0 + ni * 16 + ec;
                float v = acc[mi][ni][r];
                if (OUT_BF16)
                    ((unsigned short*)Cout)[grow * ldc + gcol] = f2b(v);
                else
                    ((float*)Cout)[grow * ldc + gcol] = v;
            }
        }
    }
}

// ---------- scan pass B: per-chunk local end states (zero-init) ----------
__global__ void scan_ends(const unsigned short* __restrict__ Hcat,
                          const float* __restrict__ lamb,
                          float* __restrict__ E) {
    const int chunk = blockIdx.x;
    const int ch = threadIdx.x << 2;   // 4 channels per thread
    float lre[4], lim[4];
#pragma unroll
    for (int i = 0; i < 4; i++) {
        float nu = expf(-expf(lamb[ch + i]));
        float th = expf(lamb[1024 + ch + i]);
        lre[i] = nu * cosf(th);
        lim[i] = nu * sinf(th);
    }
    float hr[4] = {0, 0, 0, 0}, hi[4] = {0, 0, 0, 0};
    const unsigned short* base = Hcat + (long)chunk * TCHUNK * LDH + ch;
#pragma unroll 4
    for (int t = 0; t < TCHUNK; t++) {
        ushort4 br = *(const ushort4*)(base + (long)t * LDH);
        ushort4 bi = *(const ushort4*)(base + (long)t * LDH + 1024);
        float brf[4] = {b2f(br.x), b2f(br.y), b2f(br.z), b2f(br.w)};
        float bif[4] = {b2f(bi.x), b2f(bi.y), b2f(bi.z), b2f(bi.w)};
#pragma unroll
        for (int i = 0; i < 4; i++) {
            float nr = fmaf(lre[i], hr[i], fmaf(-lim[i], hi[i], brf[i]));
            float ni = fmaf(lre[i], hi[i], fmaf(lim[i], hr[i], bif[i]));
            hr[i] = nr; hi[i] = ni;
        }
    }
    float* Ec = E + (long)chunk * 2048 + ch;
#pragma unroll
    for (int i = 0; i < 4; i++) {
        Ec[i] = hr[i];
        Ec[1024 + i] = hi[i];
    }
}

// ---------- scan pass C: sequential carry combine over chunks ----------
__global__ void carry(const float* __restrict__ lamb, const float* __restrict__ E,
                      float* __restrict__ Kc) {
    const int ch = blockIdx.x * 256 + threadIdx.x;  // 0..1023
    double nu = exp(-exp((double)lamb[ch]));
    double th = exp((double)lamb[1024 + ch]);
    double lr = nu * cos(th), li = nu * sin(th);
#pragma unroll
    for (int i = 0; i < 5; i++) {          // lambda^32
        double rr = lr * lr - li * li;
        double ii = 2.0 * lr * li;
        lr = rr; li = ii;
    }
    float tre = (float)lr, tim = (float)li;
    float hr = 0.0f, hi = 0.0f;
#pragma unroll 8
    for (int c = 0; c < NCHUNK; c++) {
        Kc[(long)c * 2048 + ch] = hr;
        Kc[(long)c * 2048 + 1024 + ch] = hi;
        float er = E[(long)c * 2048 + ch];
        float ei = E[(long)c * 2048 + 1024 + ch];
        float nr = fmaf(tre, hr, fmaf(-tim, hi, er));
        float ni = fmaf(tre, hi, fmaf(tim, hr, ei));
        hr = nr; hi = ni;
    }
}

// ---------- scan pass D: re-scan each chunk seeded with carry, IN PLACE ----------
__global__ void scan_apply(unsigned short* __restrict__ Hcat,
                           const float* __restrict__ lamb,
                           const float* __restrict__ Kc) {
    const int chunk = blockIdx.x;
    const int ch = threadIdx.x << 2;
    float lre[4], lim[4];
#pragma unroll
    for (int i = 0; i < 4; i++) {
        float nu = expf(-expf(lamb[ch + i]));
        float th = expf(lamb[1024 + ch + i]);
        lre[i] = nu * cosf(th);
        lim[i] = nu * sinf(th);
    }
    float hr[4], hi[4];
#pragma unroll
    for (int i = 0; i < 4; i++) {
        hr[i] = Kc[(long)chunk * 2048 + ch + i];
        hi[i] = Kc[(long)chunk * 2048 + 1024 + ch + i];
    }
    unsigned short* base = Hcat + (long)chunk * TCHUNK * LDH + ch;
#pragma unroll 4
    for (int t = 0; t < TCHUNK; t++) {
        ushort4 br = *(const ushort4*)(base + (long)t * LDH);
        ushort4 bi = *(const ushort4*)(base + (long)t * LDH + 1024);
        float brf[4] = {b2f(br.x), b2f(br.y), b2f(br.z), b2f(br.w)};
        float bif[4] = {b2f(bi.x), b2f(bi.y), b2f(bi.z), b2f(bi.w)};
#pragma unroll
        for (int i = 0; i < 4; i++) {
            float nr = fmaf(lre[i], hr[i], fmaf(-lim[i], hi[i], brf[i]));
            float ni = fmaf(lre[i], hi[i], fmaf(lim[i], hr[i], bif[i]));
            hr[i] = nr; hi[i] = ni;
        }
        ushort4 orv, oiv;
        orv.x = f2b(hr[0]); orv.y = f2b(hr[1]); orv.z = f2b(hr[2]); orv.w = f2b(hr[3]);
        oiv.x = f2b(hi[0]); oiv.y = f2b(hi[1]); oiv.z = f2b(hi[2]); oiv.w = f2b(hi[3]);
        *(ushort4*)(base + (long)t * LDH) = orv;
        *(ushort4*)(base + (long)t * LDH + 1024) = oiv;
    }
}

// ---------- launch ----------
extern "C" void kernel_launch(void* const* d_in, const int* in_sizes, int n_in,
                              void* d_out, int out_size, void* d_ws, size_t ws_size,
                              hipStream_t stream) {
    const float* x     = (const float*)d_in[0];  // [16384, 512]
    const float* lamb  = (const float*)d_in[1];  // [2, 1024]
    const float* gamma = (const float*)d_in[2];  // [1024]
    const float* B_re  = (const float*)d_in[3];  // [1024, 512]
    const float* B_im  = (const float*)d_in[4];
    const float* C_re  = (const float*)d_in[5];  // [512, 1024]
    const float* C_im  = (const float*)d_in[6];
    const float* Dm    = (const float*)d_in[7];  // [512, 512]

    char* ws = (char*)d_ws;
    unsigned short* Hcat = (unsigned short*)ws;                      // 16384*2560*2 = 83886080
    float* E  = (float*)(ws + 83886080);                             // 512*2048*4 = 4194304
    float* Kc = E + (long)NCHUNK * 2048;                             // 4194304
    unsigned short* Bcat = (unsigned short*)((char*)Kc + 4194304);   // 2048*512*2 = 2097152
    unsigned short* CW   = Bcat + (long)2048 * 512;                  // 512*2560*2 = 2621440

    prep_all<<<10496, 256, 0, stream>>>(x, B_re, B_im, gamma, C_re, C_im, Dm, Hcat, Bcat, CW);
    // Bu = x_bf16 @ Bcat^T -> Hcat cols [0,2048).  grid 256(by) x 16(bx) = 4096 single-wave blocks.
    gemm_w64<true><<<4096, 64, 0, stream>>>(Hcat + 2048, LDH, Bcat, 512, Hcat, LDH, 512,
                                            /*nbx_shift=*/4);
    scan_ends<<<NCHUNK, 256, 0, stream>>>(Hcat, lamb, E);
    carry<<<4, 256, 0, stream>>>(lamb, E, Kc);
    scan_apply<<<NCHUNK, 256, 0, stream>>>(Hcat, lamb, Kc);
    // y = Hcat @ CW^T -> d_out f32.  grid 256(by) x 4(bx) = 1024 single-wave blocks.
    gemm_w64<false><<<1024, 64, 0, stream>>>(Hcat, LDH, CW, 2560, (float*)d_out, 512, 2560,
                                             /*nbx_shift=*/2);
}